// Round 1
// baseline (503.690 us; speedup 1.0000x reference)
//
#include <hip/hip_runtime.h>
#include <hip/hip_bf16.h>

typedef __attribute__((ext_vector_type(8))) __bf16 bf16x8;
typedef __attribute__((ext_vector_type(4))) float f32x4;
typedef unsigned short u16;
typedef unsigned int u32;

#define DMODEL 1024
#define SLEN   2048
#define NPROJ  11264
#define NFUSE  5120
#define MROWS  4096

__device__ __forceinline__ float b2f(u16 u){ u32 v=((u32)u)<<16; float f; __builtin_memcpy(&f,&v,4); return f; }
__device__ __forceinline__ u16 f2b(float f){ u32 u; __builtin_memcpy(&u,&f,4); u32 r=u+0x7fffu+((u>>16)&1u); return (u16)(r>>16); }

__device__ __forceinline__ void gload16(const void* g, void* l){
  __builtin_amdgcn_global_load_lds((__attribute__((address_space(1))) u32*)g,
                                   (__attribute__((address_space(3))) u32*)l, 16, 0, 0);
}

// ---------------- transpose+cast fp32 (K,N) -> bf16 (N, ldd) at column offset ----------------
__global__ __launch_bounds__(256) void k_transpose(const float* __restrict__ src, int N,
                                                   u16* __restrict__ dst, int ldd, int coloff){
  __shared__ float tile[32][33];
  int n0 = blockIdx.x*32, k0 = blockIdx.y*32;
  int tx = threadIdx.x & 31, ty = threadIdx.x >> 5;
  #pragma unroll
  for (int r=0;r<4;r++)
    tile[ty*4+r][tx] = src[(size_t)(k0+ty*4+r)*N + n0 + tx];
  __syncthreads();
  #pragma unroll
  for (int r=0;r<4;r++){
    int n = ty*4+r;
    dst[(size_t)(n0+n)*ldd + coloff + k0 + tx] = f2b(tile[tx][n]);
  }
}

// ---------------- rope cos/sin table: tab[s*32 + i]=cos, tab[s*32+16+i]=sin ----------------
__global__ __launch_bounds__(256) void k_rope_table(float* __restrict__ tab){
  int idx = blockIdx.x*256 + threadIdx.x;
  if (idx >= SLEN*16) return;
  int s = idx >> 4, i = idx & 15;
  float inv = powf(10000.f, -(float)i/16.f);
  float f = (float)s * inv;
  tab[s*32 + i]      = cosf(f);
  tab[s*32 + 16 + i] = sinf(f);
}

// ---------------- cond = silu(te) @ cond_w + cond_b  (B x 2048 fp32) ----------------
__global__ __launch_bounds__(256) void k_cond(const float* __restrict__ te, const float* __restrict__ cw,
                                              const float* __restrict__ cb, float* __restrict__ cond){
  __shared__ float sl[DMODEL];
  int b = blockIdx.y, t = threadIdx.x;
  for (int i=t;i<DMODEL;i+=256){ float x = te[b*DMODEL+i]; sl[i] = x/(1.f+expf(-x)); }
  __syncthreads();
  int n = blockIdx.x*256 + t;
  float acc = 0.f;
  for (int k=0;k<DMODEL;k++) acc += sl[k]*cw[(size_t)k*2048 + n];
  cond[b*2048+n] = acc + cb[n];
}

// ---------------- LayerNorm + (1+scale)*x + bias -> units bf16 ----------------
__global__ __launch_bounds__(256) void k_ln(const float* __restrict__ x, const float* __restrict__ lw,
                                            const float* __restrict__ lb, const float* __restrict__ cond,
                                            u16* __restrict__ units){
  int row = blockIdx.x; int b = row >> 11;
  int t = threadIdx.x;
  const float4 v = *(const float4*)(x + (size_t)row*DMODEL + t*4);
  float s = v.x+v.y+v.z+v.w;
  float q = v.x*v.x+v.y*v.y+v.z*v.z+v.w*v.w;
  #pragma unroll
  for (int off=32; off; off>>=1){ s += __shfl_xor(s,off); q += __shfl_xor(q,off); }
  __shared__ float red[8];
  int w = t>>6, l = t&63;
  if (l==0){ red[w]=s; red[4+w]=q; }
  __syncthreads();
  float S = red[0]+red[1]+red[2]+red[3];
  float Q = red[4]+red[5]+red[6]+red[7];
  float mu = S*(1.f/1024.f);
  float var = Q*(1.f/1024.f) - mu*mu;
  float rstd = rsqrtf(var + 1e-5f);
  int c0 = t*4;
  u16 o[4];
  const float* vf = (const float*)&v;
  #pragma unroll
  for (int i=0;i<4;i++){
    int c = c0+i;
    float nrm = (vf[i]-mu)*rstd*lw[c] + lb[c];
    float outv = (1.f + cond[b*2048 + c])*nrm + cond[b*2048 + 1024 + c];
    o[i] = f2b(outv);
  }
  u32 p0 = (u32)o[0] | ((u32)o[1]<<16);
  u32 p1 = (u32)o[2] | ((u32)o[3]<<16);
  uint2 pk; pk.x = p0; pk.y = p1;
  *(uint2*)(units + (size_t)row*DMODEL + c0) = pk;
}

// ---------------- GEMM: C[M,N] = A[M,K] @ Bt[N,K]^T, bf16 in, 128x128 tile ----------------
// EPI 0: store bf16 to Cb (ldc). EPI 1: outF = acc + resid + bias (fp32, ld 1024)
template<int EPI>
__global__ __launch_bounds__(256) void k_gemm(const u16* __restrict__ A, const u16* __restrict__ Bt,
                                              int K, int ldc, u16* __restrict__ Cb,
                                              float* __restrict__ outF, const float* __restrict__ resid,
                                              const float* __restrict__ bias){
  __shared__ __attribute__((aligned(16))) u16 Asm[128*32];
  __shared__ __attribute__((aligned(16))) u16 Bsm[128*32];
  int t = threadIdx.x, w = t>>6, l = t&63;
  int wr = w>>1, wc = w&1;
  size_t m0 = (size_t)blockIdx.y*128, n0 = (size_t)blockIdx.x*128;
  const u16* Ab = A + m0*(size_t)K;
  const u16* Bb = Bt + n0*(size_t)K;
  f32x4 zero = {0.f,0.f,0.f,0.f};
  f32x4 acc[4][4];
  #pragma unroll
  for (int i=0;i<4;i++)
    #pragma unroll
    for (int j=0;j<4;j++) acc[i][j] = zero;

  for (int k0=0; k0<K; k0+=32){
    #pragma unroll
    for (int r=0;r<2;r++){
      int c = r*256 + t;
      int row = c>>2;
      int g = (c&3) ^ ((row>>1)&3);           // XOR-swizzled source granule
      gload16(Ab + (size_t)row*K + k0 + g*8, (char*)Asm + r*4096 + w*1024);
      gload16(Bb + (size_t)row*K + k0 + g*8, (char*)Bsm + r*4096 + w*1024);
    }
    __syncthreads();
    bf16x8 af[4], bfr[4];
    #pragma unroll
    for (int i=0;i<4;i++){
      int ra = wr*64 + i*16 + (l&15);
      int ga = (l>>4) ^ ((ra>>1)&3);
      af[i] = *(const bf16x8*)(Asm + ra*32 + ga*8);
      int rb = wc*64 + i*16 + (l&15);
      int gb = (l>>4) ^ ((rb>>1)&3);
      bfr[i] = *(const bf16x8*)(Bsm + rb*32 + gb*8);
    }
    #pragma unroll
    for (int i=0;i<4;i++)
      #pragma unroll
      for (int j=0;j<4;j++)
        acc[i][j] = __builtin_amdgcn_mfma_f32_16x16x32_bf16(af[i], bfr[j], acc[i][j], 0,0,0);
    __syncthreads();
  }
  #pragma unroll
  for (int i=0;i<4;i++)
    #pragma unroll
    for (int j=0;j<4;j++)
      #pragma unroll
      for (int r=0;r<4;r++){
        size_t row = m0 + wr*64 + i*16 + (l>>4)*4 + r;
        size_t col = n0 + wc*64 + j*16 + (l&15);
        float v = acc[i][j][r];
        if (EPI==0) Cb[row*(size_t)ldc + col] = f2b(v);
        else        outF[row*DMODEL + col] = v + resid[row*DMODEL + col] + bias[col];
      }
}

// ---------------- repack: proj -> qh,kh (B,H,S,64, roped, q*0.125), vT (B,H,64,S) ----------------
__global__ __launch_bounds__(256) void k_repack(const u16* __restrict__ proj, const float* __restrict__ tab,
                                                u16* __restrict__ qh, u16* __restrict__ kh,
                                                u16* __restrict__ vt){
  int b = blockIdx.z, h = blockIdx.y, s0 = blockIdx.x*64;
  int t = threadIdx.x;
  int sl = t>>2, quad = t&3;
  int s = s0 + sl;
  const u16* prow = proj + (size_t)(b*SLEN+s)*NPROJ;
  size_t headoff = ((size_t)(b*16+h)*SLEN + s)*64;
  #pragma unroll
  for (int pass=0; pass<2; pass++){
    int coff = (pass==0) ? h*64 : DMODEL + h*64;
    u16* dst = (pass==0) ? qh : kh;
    float sc = (pass==0) ? 0.125f : 1.0f;
    #pragma unroll
    for (int i=0;i<16;i++){
      int d = quad*16 + i;
      float xv = b2f(prow[coff + d]);
      float o;
      if (d < 16){
        float y = b2f(prow[coff + d + 16]);
        o = xv*tab[s*32+d] - y*tab[s*32+16+d];
      } else if (d < 32){
        int j = d-16;
        float y = b2f(prow[coff + j]);
        o = xv*tab[s*32+j] + y*tab[s*32+16+j];
      } else o = xv;
      dst[headoff + d] = f2b(o*sc);
    }
  }
  __shared__ u16 vt_lds[64][72];
  {
    int coff = 2*DMODEL + h*64;
    #pragma unroll
    for (int i=0;i<16;i++){
      int d = quad*16+i;
      vt_lds[d][sl] = prow[coff + d];
    }
  }
  __syncthreads();
  {
    int d = t>>2, sg = t&3;
    size_t base = ((size_t)(b*16+h)*64 + d)*SLEN + s0 + sg*16;
    #pragma unroll
    for (int i=0;i<16;i++)
      vt[base + i] = vt_lds[d][sg*16+i];
  }
}

// ---------------- ff * gelu_tanh(gate) -> Afinal cols 1024..5119 ----------------
__global__ __launch_bounds__(256) void k_ffgate(const u16* __restrict__ proj, u16* __restrict__ afinal){
  int row = blockIdx.y;
  int c0 = (blockIdx.x*256 + threadIdx.x)*8;
  const u16* pr = proj + (size_t)row*NPROJ;
  uint4 aff = *(const uint4*)(pr + 3072 + c0);
  uint4 ag  = *(const uint4*)(pr + 7168 + c0);
  const u16* pf = (const u16*)&aff;
  const u16* pg = (const u16*)&ag;
  union { u16 o[8]; uint4 v; } out;
  #pragma unroll
  for (int i=0;i<8;i++){
    float fv = b2f(pf[i]);
    float gv = b2f(pg[i]);
    float tz = 0.7978845608f*(gv + 0.044715f*gv*gv*gv);
    float th = 1.f - 2.f/(__expf(2.f*tz)+1.f);
    out.o[i] = f2b(fv * 0.5f*gv*(1.f+th));
  }
  *(uint4*)(afinal + (size_t)row*NFUSE + DMODEL + c0) = out.v;
}

// ---------------- flash attention: 1 block per (b,h,64 q rows), 4 waves x 16 rows ----------------
__global__ __launch_bounds__(256) void k_attn(const u16* __restrict__ qh, const u16* __restrict__ kh,
                                              const u16* __restrict__ vt, u16* __restrict__ afinal){
  __shared__ __attribute__((aligned(16))) u16 Klds[64*64];
  __shared__ __attribute__((aligned(16))) u16 Vlds[64*64];
  __shared__ __attribute__((aligned(16))) u16 Plds[4][16*72];
  int b = blockIdx.z, h = blockIdx.y, q0 = blockIdx.x*64;
  int t = threadIdx.x, w = t>>6, l = t&63;
  size_t hoff = (size_t)(b*16+h)*SLEN*64;
  const u16* Qb = qh + hoff + (size_t)(q0 + w*16)*64;
  const u16* Kb = kh + hoff;
  const u16* Vb = vt + hoff;
  bf16x8 qf[2];
  #pragma unroll
  for (int ks=0;ks<2;ks++)
    qf[ks] = *(const bf16x8*)(Qb + (size_t)(l&15)*64 + ks*32 + (l>>4)*8);
  f32x4 zero = {0.f,0.f,0.f,0.f};
  f32x4 acc[4];
  float mj[4], lj[4];
  #pragma unroll
  for (int n=0;n<4;n++) acc[n] = zero;
  #pragma unroll
  for (int j=0;j<4;j++){ mj[j] = -1e30f; lj[j] = 0.f; }

  for (int kv0=0; kv0<SLEN; kv0+=64){
    __syncthreads();
    #pragma unroll
    for (int r=0;r<2;r++){
      int c = r*256 + t;
      int row = c>>3;
      int g = (c&7) ^ (row&7);
      gload16(Kb + (size_t)(kv0+row)*64 + g*8, (char*)Klds + r*4096 + w*1024);
      gload16(Vb + (size_t)row*SLEN + kv0 + g*8, (char*)Vlds + r*4096 + w*1024);
    }
    __syncthreads();
    f32x4 sf[4];
    #pragma unroll
    for (int n=0;n<4;n++){
      sf[n] = zero;
      #pragma unroll
      for (int ks=0;ks<2;ks++){
        int rk = n*16 + (l&15);
        int g = (ks*4 + (l>>4)) ^ (rk&7);
        bf16x8 kf = *(const bf16x8*)(Klds + rk*64 + g*8);
        sf[n] = __builtin_amdgcn_mfma_f32_16x16x32_bf16(qf[ks], kf, sf[n], 0,0,0);
      }
    }
    #pragma unroll
    for (int j=0;j<4;j++){
      float pm = fmaxf(fmaxf(sf[0][j], sf[1][j]), fmaxf(sf[2][j], sf[3][j]));
      pm = fmaxf(pm, __shfl_xor(pm,1)); pm = fmaxf(pm, __shfl_xor(pm,2));
      pm = fmaxf(pm, __shfl_xor(pm,4)); pm = fmaxf(pm, __shfl_xor(pm,8));
      float mn = fmaxf(mj[j], pm);
      float corr = __expf(mj[j]-mn);
      mj[j] = mn;
      float rs = 0.f;
      #pragma unroll
      for (int n=0;n<4;n++){
        float p = __expf(sf[n][j]-mn);
        sf[n][j] = p; rs += p;
      }
      rs += __shfl_xor(rs,1); rs += __shfl_xor(rs,2);
      rs += __shfl_xor(rs,4); rs += __shfl_xor(rs,8);
      lj[j] = lj[j]*corr + rs;
      #pragma unroll
      for (int n=0;n<4;n++) acc[n][j] *= corr;
    }
    #pragma unroll
    for (int j=0;j<4;j++)
      #pragma unroll
      for (int n=0;n<4;n++)
        Plds[w][((l>>4)*4+j)*72 + n*16 + (l&15)] = f2b(sf[n][j]);
    #pragma unroll
    for (int ks=0;ks<2;ks++){
      bf16x8 pf = *(const bf16x8*)(&Plds[w][(l&15)*72 + ks*32 + (l>>4)*8]);
      #pragma unroll
      for (int n=0;n<4;n++){
        int rv = n*16 + (l&15);
        int g = (ks*4 + (l>>4)) ^ (rv&7);
        bf16x8 vf = *(const bf16x8*)(Vlds + rv*64 + g*8);
        acc[n] = __builtin_amdgcn_mfma_f32_16x16x32_bf16(pf, vf, acc[n], 0,0,0);
      }
    }
  }
  #pragma unroll
  for (int n=0;n<4;n++)
    #pragma unroll
    for (int j=0;j<4;j++){
      int srow = q0 + w*16 + (l>>4)*4 + j;
      int col = h*64 + n*16 + (l&15);
      float v = acc[n][j] / lj[j];
      afinal[(size_t)(b*SLEN+srow)*NFUSE + col] = f2b(v);
    }
}

// ---------------- launch ----------------
extern "C" void kernel_launch(void* const* d_in, const int* in_sizes, int n_in,
                              void* d_out, int out_size, void* d_ws, size_t ws_size,
                              hipStream_t stream) {
  const float* inputs = (const float*)d_in[0];
  const float* te     = (const float*)d_in[1];
  const float* ln_w   = (const float*)d_in[2];
  const float* ln_b   = (const float*)d_in[3];
  const float* cond_w = (const float*)d_in[4];
  const float* cond_b = (const float*)d_in[5];
  const float* w_in   = (const float*)d_in[6];
  const float* w_attn = (const float*)d_in[7];
  const float* w_ff   = (const float*)d_in[8];
  const float* b_ff   = (const float*)d_in[9];
  float* out = (float*)d_out;

  char* ws = (char*)d_ws;
  size_t off = 0;
  auto alloc = [&](size_t n)->char*{ char* p = ws + off; off += (n + 255) & ~(size_t)255; return p; };
  u16*  w_inT    = (u16*)alloc((size_t)NPROJ*DMODEL*2);
  u16*  w_fusedT = (u16*)alloc((size_t)DMODEL*NFUSE*2);
  u16*  units    = (u16*)alloc((size_t)MROWS*DMODEL*2);
  u16*  proj     = (u16*)alloc((size_t)MROWS*NPROJ*2);
  u16*  qh       = (u16*)alloc((size_t)MROWS*DMODEL*2);
  u16*  kh       = (u16*)alloc((size_t)MROWS*DMODEL*2);
  u16*  vT       = (u16*)alloc((size_t)MROWS*DMODEL*2);
  u16*  afinal   = (u16*)alloc((size_t)MROWS*NFUSE*2);
  float* cond    = (float*)alloc(2*2048*4);
  float* ropetab = (float*)alloc((size_t)SLEN*32*4);
  (void)ws_size; (void)in_sizes; (void)n_in; (void)out_size;

  // weight prep
  k_transpose<<<dim3(NPROJ/32, DMODEL/32), 256, 0, stream>>>(w_in, NPROJ, w_inT, DMODEL, 0);
  k_transpose<<<dim3(DMODEL/32, DMODEL/32), 256, 0, stream>>>(w_attn, DMODEL, w_fusedT, NFUSE, 0);
  k_transpose<<<dim3(DMODEL/32, 4096/32), 256, 0, stream>>>(w_ff, DMODEL, w_fusedT, NFUSE, DMODEL);
  k_rope_table<<<128, 256, 0, stream>>>(ropetab);
  // conditioning + LN
  k_cond<<<dim3(8,2), 256, 0, stream>>>(te, cond_w, cond_b, cond);
  k_ln<<<MROWS, 256, 0, stream>>>(inputs, ln_w, ln_b, cond, units);
  // fused qkv/ff projection
  k_gemm<0><<<dim3(NPROJ/128, MROWS/128), 256, 0, stream>>>(units, w_inT, DMODEL, NPROJ, proj,
                                                            nullptr, nullptr, nullptr);
  // rope + head split + v transpose; ff gating
  k_repack<<<dim3(SLEN/64, 16, 2), 256, 0, stream>>>(proj, ropetab, qh, kh, vT);
  k_ffgate<<<dim3(2, MROWS), 256, 0, stream>>>(proj, afinal);
  // attention -> afinal cols 0..1023
  k_attn<<<dim3(SLEN/64, 16, 2), 256, 0, stream>>>(qh, kh, vT, afinal);
  // final fused GEMM: out = afinal @ w_fusedT^T + inputs + b_ff
  k_gemm<1><<<dim3(DMODEL/128, MROWS/128), 256, 0, stream>>>(afinal, w_fusedT, NFUSE, 0, nullptr,
                                                             out, inputs, b_ff);
}

// Round 2
// 433.028 us; speedup vs baseline: 1.1632x; 1.1632x over previous
//
#include <hip/hip_runtime.h>
#include <hip/hip_bf16.h>

typedef __attribute__((ext_vector_type(8))) __bf16 bf16x8;
typedef __attribute__((ext_vector_type(4))) float f32x4;
typedef unsigned short u16;
typedef unsigned int u32;

#define DMODEL 1024
#define SLEN   2048
#define NPROJ  11264
#define NFUSE  5120
#define MROWS  4096

__device__ __forceinline__ float b2f(u16 u){ u32 v=((u32)u)<<16; float f; __builtin_memcpy(&f,&v,4); return f; }
__device__ __forceinline__ u16 f2b(float f){ u32 u; __builtin_memcpy(&u,&f,4); u32 r=u+0x7fffu+((u>>16)&1u); return (u16)(r>>16); }

__device__ __forceinline__ void gload16(const void* g, void* l){
  __builtin_amdgcn_global_load_lds((__attribute__((address_space(1))) u32*)g,
                                   (__attribute__((address_space(3))) u32*)l, 16, 0, 0);
}

// ---------------- transpose+cast fp32 (K,N) -> bf16 (N, ldd) at column offset ----------------
// REMAP=1: dst row nn >= 3072 pulls from interleaved ff/gate columns of w_in
template<int REMAP>
__global__ __launch_bounds__(256) void k_transpose(const float* __restrict__ src, int N,
                                                   u16* __restrict__ dst, int ldd, int coloff){
  __shared__ float tile[32][33];
  int n0 = blockIdx.x*32, k0 = blockIdx.y*32;
  int tx = threadIdx.x & 31, ty = threadIdx.x >> 5;
  int srccol;
  if (REMAP && (n0 + tx) >= 3072){
    int c = n0 + tx - 3072;
    int q = c >> 5, o = c & 31;
    srccol = (o < 16) ? (3072 + 16*q + o) : (7168 + 16*q + (o-16));
  } else srccol = n0 + tx;
  #pragma unroll
  for (int r=0;r<4;r++)
    tile[ty*4+r][tx] = src[(size_t)(k0+ty*4+r)*N + srccol];
  __syncthreads();
  #pragma unroll
  for (int r=0;r<4;r++){
    int n = ty*4+r;
    dst[(size_t)(n0+n)*ldd + coloff + k0 + tx] = f2b(tile[tx][n]);
  }
}

// ---------------- rope cos/sin table: tab[s*32 + i]=cos, tab[s*32+16+i]=sin ----------------
__global__ __launch_bounds__(256) void k_rope_table(float* __restrict__ tab){
  int idx = blockIdx.x*256 + threadIdx.x;
  if (idx >= SLEN*16) return;
  int s = idx >> 4, i = idx & 15;
  float inv = powf(10000.f, -(float)i/16.f);
  float f = (float)s * inv;
  tab[s*32 + i]      = cosf(f);
  tab[s*32 + 16 + i] = sinf(f);
}

// ---------------- cond = silu(te) @ cond_w + cond_b  (B x 2048 fp32) ----------------
__global__ __launch_bounds__(256) void k_cond(const float* __restrict__ te, const float* __restrict__ cw,
                                              const float* __restrict__ cb, float* __restrict__ cond){
  __shared__ float sl[DMODEL];
  int b = blockIdx.y, t = threadIdx.x;
  for (int i=t;i<DMODEL;i+=256){ float x = te[b*DMODEL+i]; sl[i] = x/(1.f+expf(-x)); }
  __syncthreads();
  int n = blockIdx.x*256 + t;
  float acc = 0.f;
  for (int k=0;k<DMODEL;k++) acc += sl[k]*cw[(size_t)k*2048 + n];
  cond[b*2048+n] = acc + cb[n];
}

// ---------------- LayerNorm + (1+scale)*x + bias -> units bf16 ----------------
__global__ __launch_bounds__(256) void k_ln(const float* __restrict__ x, const float* __restrict__ lw,
                                            const float* __restrict__ lb, const float* __restrict__ cond,
                                            u16* __restrict__ units){
  int row = blockIdx.x; int b = row >> 11;
  int t = threadIdx.x;
  const float4 v = *(const float4*)(x + (size_t)row*DMODEL + t*4);
  float s = v.x+v.y+v.z+v.w;
  float q = v.x*v.x+v.y*v.y+v.z*v.z+v.w*v.w;
  #pragma unroll
  for (int off=32; off; off>>=1){ s += __shfl_xor(s,off); q += __shfl_xor(q,off); }
  __shared__ float red[8];
  int w = t>>6, l = t&63;
  if (l==0){ red[w]=s; red[4+w]=q; }
  __syncthreads();
  float S = red[0]+red[1]+red[2]+red[3];
  float Q = red[4]+red[5]+red[6]+red[7];
  float mu = S*(1.f/1024.f);
  float var = Q*(1.f/1024.f) - mu*mu;
  float rstd = rsqrtf(var + 1e-5f);
  int c0 = t*4;
  u16 o[4];
  const float* vf = (const float*)&v;
  #pragma unroll
  for (int i=0;i<4;i++){
    int c = c0+i;
    float nrm = (vf[i]-mu)*rstd*lw[c] + lb[c];
    float outv = (1.f + cond[b*2048 + c])*nrm + cond[b*2048 + 1024 + c];
    o[i] = f2b(outv);
  }
  u32 p0 = (u32)o[0] | ((u32)o[1]<<16);
  u32 p1 = (u32)o[2] | ((u32)o[3]<<16);
  uint2 pk; pk.x = p0; pk.y = p1;
  *(uint2*)(units + (size_t)row*DMODEL + c0) = pk;
}

// ================= core 128x128 bf16 GEMM loop (m97 structure) =================
#define GEMM_CORE(AB, BB, KLEN, LDA, LDB)                                         \
  for (int k0=0; k0<(KLEN); k0+=32){                                              \
    _Pragma("unroll")                                                             \
    for (int r=0;r<2;r++){                                                        \
      int c = r*256 + t;                                                          \
      int row = c>>2;                                                             \
      int g = (c&3) ^ ((row>>1)&3);                                               \
      gload16((AB) + (size_t)row*(LDA) + k0 + g*8, (char*)Asm + r*4096 + w*1024); \
      gload16((BB) + (size_t)row*(LDB) + k0 + g*8, (char*)Bsm + r*4096 + w*1024); \
    }                                                                             \
    __syncthreads();                                                              \
    bf16x8 af[4], bfr[4];                                                         \
    _Pragma("unroll")                                                             \
    for (int i=0;i<4;i++){                                                        \
      int ra = wr*64 + i*16 + (l&15);                                             \
      int ga = (l>>4) ^ ((ra>>1)&3);                                              \
      af[i] = *(const bf16x8*)(Asm + ra*32 + ga*8);                               \
      int rb = wc*64 + i*16 + (l&15);                                             \
      int gb = (l>>4) ^ ((rb>>1)&3);                                              \
      bfr[i] = *(const bf16x8*)(Bsm + rb*32 + gb*8);                              \
    }                                                                             \
    _Pragma("unroll")                                                             \
    for (int i=0;i<4;i++)                                                         \
      _Pragma("unroll")                                                           \
      for (int j=0;j<4;j++)                                                       \
        acc[i][j] = __builtin_amdgcn_mfma_f32_16x16x32_bf16(af[i], bfr[j], acc[i][j], 0,0,0); \
    __syncthreads();                                                              \
  }

// ---------------- proj GEMM with fused rope/head-split/V/ff-gate epilogue ----------------
__global__ __launch_bounds__(256) void k_gemm_proj(const u16* __restrict__ A, const u16* __restrict__ Bt,
                                                   const float* __restrict__ tab,
                                                   u16* __restrict__ qh, u16* __restrict__ kh,
                                                   u16* __restrict__ vq, u16* __restrict__ afinal){
  __shared__ __attribute__((aligned(16))) u16 Asm[128*32];
  __shared__ __attribute__((aligned(16))) u16 Bsm[128*32];
  int t = threadIdx.x, w = t>>6, l = t&63;
  int wr = w>>1, wc = w&1;
  int m0 = blockIdx.y*128, n0 = blockIdx.x*128;
  const u16* Ab = A + (size_t)m0*DMODEL;
  const u16* Bb = Bt + (size_t)n0*DMODEL;
  f32x4 zero = {0.f,0.f,0.f,0.f};
  f32x4 acc[4][4];
  #pragma unroll
  for (int i=0;i<4;i++)
    #pragma unroll
    for (int j=0;j<4;j++) acc[i][j] = zero;

  GEMM_CORE(Ab, Bb, DMODEL, DMODEL, DMODEL)

  int region = (n0 < 1024) ? 0 : (n0 < 2048) ? 1 : (n0 < 3072) ? 2 : 3;
  if (region <= 1){
    u16* dst = (region==0) ? qh : kh;
    float sc = (region==0) ? 0.125f : 1.0f;
    int h = (n0 - region*1024 + wc*64) >> 6;
    int d = l&15;
    #pragma unroll
    for (int i=0;i<4;i++){
      #pragma unroll
      for (int r=0;r<4;r++){
        int row = m0 + wr*64 + i*16 + (l>>4)*4 + r;
        int b = row>>11, s = row&2047;
        float cs = tab[s*32+d], sn = tab[s*32+16+d];
        float x0 = acc[i][0][r], x1 = acc[i][1][r];
        size_t base = ((size_t)(b*16+h)*SLEN + s)*64;
        dst[base + d]      = f2b((x0*cs - x1*sn)*sc);
        dst[base + 16 + d] = f2b((x1*cs + x0*sn)*sc);
        dst[base + 32 + d] = f2b(acc[i][2][r]*sc);
        dst[base + 48 + d] = f2b(acc[i][3][r]*sc);
      }
    }
  } else if (region == 2){
    #pragma unroll
    for (int i=0;i<4;i++)
      #pragma unroll
      for (int j=0;j<4;j++){
        int cv = (n0-2048) + wc*64 + j*16 + (l&15);
        #pragma unroll
        for (int r=0;r<4;r++){
          int row = m0 + wr*64 + i*16 + (l>>4)*4 + r;
          vq[(size_t)row*DMODEL + cv] = f2b(acc[i][j][r]);
        }
      }
  } else {
    int fbase = (n0-3072)/2 + wc*32 + (l&15);
    #pragma unroll
    for (int i=0;i<4;i++)
      #pragma unroll
      for (int p=0;p<2;p++){
        int col = 1024 + fbase + p*16;
        #pragma unroll
        for (int r=0;r<4;r++){
          int row = m0 + wr*64 + i*16 + (l>>4)*4 + r;
          float fv = acc[i][2*p][r];
          float gv = acc[i][2*p+1][r];
          float tz = 0.7978845608f*(gv + 0.044715f*gv*gv*gv);
          float th = 1.f - 2.f/(__expf(2.f*tz)+1.f);
          afinal[(size_t)row*NFUSE + col] = f2b(fv * 0.5f*gv*(1.f+th));
        }
      }
  }
}

// ---------------- split-K GEMM: fp32 partials ----------------
__global__ __launch_bounds__(256) void k_gemm_split(const u16* __restrict__ A, const u16* __restrict__ Bt,
                                                    float* __restrict__ pb){
  __shared__ __attribute__((aligned(16))) u16 Asm[128*32];
  __shared__ __attribute__((aligned(16))) u16 Bsm[128*32];
  int t = threadIdx.x, w = t>>6, l = t&63;
  int wr = w>>1, wc = w&1;
  int m0 = blockIdx.y*128, n0 = blockIdx.x*128;
  int slice = blockIdx.z;
  const u16* Ab = A + (size_t)m0*NFUSE + slice*1280;
  const u16* Bb = Bt + (size_t)n0*NFUSE + slice*1280;
  f32x4 zero = {0.f,0.f,0.f,0.f};
  f32x4 acc[4][4];
  #pragma unroll
  for (int i=0;i<4;i++)
    #pragma unroll
    for (int j=0;j<4;j++) acc[i][j] = zero;

  GEMM_CORE(Ab, Bb, 1280, NFUSE, NFUSE)

  float* pbs = pb + (size_t)slice*MROWS*DMODEL;
  #pragma unroll
  for (int i=0;i<4;i++)
    #pragma unroll
    for (int j=0;j<4;j++){
      int col = n0 + wc*64 + j*16 + (l&15);
      #pragma unroll
      for (int r=0;r<4;r++){
        int row = m0 + wr*64 + i*16 + (l>>4)*4 + r;
        pbs[(size_t)row*DMODEL + col] = acc[i][j][r];
      }
    }
}

// ---------------- reduce partials + residual + bias ----------------
__global__ __launch_bounds__(256) void k_reduce(const float* __restrict__ pb, const float* __restrict__ resid,
                                                const float* __restrict__ bias, float* __restrict__ out){
  size_t i4 = ((size_t)blockIdx.x*256 + threadIdx.x)*4;
  float4 a0 = *(const float4*)(pb + i4);
  float4 a1 = *(const float4*)(pb + (size_t)MROWS*DMODEL + i4);
  float4 a2 = *(const float4*)(pb + (size_t)2*MROWS*DMODEL + i4);
  float4 a3 = *(const float4*)(pb + (size_t)3*MROWS*DMODEL + i4);
  float4 rv = *(const float4*)(resid + i4);
  float4 bv = *(const float4*)(bias + (i4 & 1023));
  float4 o;
  o.x = a0.x+a1.x+a2.x+a3.x+rv.x+bv.x;
  o.y = a0.y+a1.y+a2.y+a3.y+rv.y+bv.y;
  o.z = a0.z+a1.z+a2.z+a3.z+rv.z+bv.z;
  o.w = a0.w+a1.w+a2.w+a3.w+rv.w+bv.w;
  *(float4*)(out + i4) = o;
}

// ---------------- V transpose: vq (B,S,1024) -> vT (B,H,64,S) ----------------
__global__ __launch_bounds__(256) void k_vtrans(const u16* __restrict__ vq, u16* __restrict__ vt){
  int b = blockIdx.z, h = blockIdx.y, s0 = blockIdx.x*64;
  int t = threadIdx.x;
  __shared__ u16 vt_lds[64][72];
  int sl = t>>2, quad = t&3;
  const u16* prow = vq + (size_t)(b*SLEN + s0 + sl)*DMODEL + h*64;
  #pragma unroll
  for (int i=0;i<16;i++){
    int d = quad*16+i;
    vt_lds[d][sl] = prow[d];
  }
  __syncthreads();
  int d = t>>2, sg = t&3;
  size_t base = ((size_t)(b*16+h)*64 + d)*SLEN + s0 + sg*16;
  #pragma unroll
  for (int i=0;i<16;i++)
    vt[base + i] = vt_lds[d][sg*16+i];
}

// ---------------- flash attention: dbuf staging + setprio ----------------
__global__ __launch_bounds__(256) void k_attn(const u16* __restrict__ qh, const u16* __restrict__ kh,
                                              const u16* __restrict__ vt, u16* __restrict__ afinal){
  __shared__ __attribute__((aligned(16))) u16 Klds[2][64*64];
  __shared__ __attribute__((aligned(16))) u16 Vlds[2][64*64];
  __shared__ __attribute__((aligned(16))) u16 Plds[4][16*72];
  int b = blockIdx.z, h = blockIdx.y, q0 = blockIdx.x*64;
  int t = threadIdx.x, w = t>>6, l = t&63;
  size_t hoff = (size_t)(b*16+h)*SLEN*64;
  const u16* Qb = qh + hoff + (size_t)(q0 + w*16)*64;
  const u16* Kb = kh + hoff;
  const u16* Vb = vt + hoff;
  bf16x8 qf[2];
  #pragma unroll
  for (int ks=0;ks<2;ks++)
    qf[ks] = *(const bf16x8*)(Qb + (size_t)(l&15)*64 + ks*32 + (l>>4)*8);
  f32x4 zero = {0.f,0.f,0.f,0.f};
  f32x4 acc[4];
  float mj[4], lj[4];
  #pragma unroll
  for (int n=0;n<4;n++) acc[n] = zero;
  #pragma unroll
  for (int j=0;j<4;j++){ mj[j] = -1e30f; lj[j] = 0.f; }

  auto STAGE = [&](int buf, int kv0){
    #pragma unroll
    for (int r=0;r<2;r++){
      int c = r*256 + t;
      int row = c>>3;
      int g = (c&7) ^ (row&7);
      gload16(Kb + (size_t)(kv0+row)*64 + g*8, (char*)Klds[buf] + r*4096 + w*1024);
      gload16(Vb + (size_t)row*SLEN + kv0 + g*8, (char*)Vlds[buf] + r*4096 + w*1024);
    }
  };

  STAGE(0, 0);
  __syncthreads();

  for (int tile=0; tile<SLEN/64; ++tile){
    int cur = tile & 1;
    if (tile+1 < SLEN/64) STAGE(cur^1, (tile+1)*64);
    f32x4 sf[4];
    __builtin_amdgcn_s_setprio(1);
    #pragma unroll
    for (int n=0;n<4;n++){
      sf[n] = zero;
      #pragma unroll
      for (int ks=0;ks<2;ks++){
        int rk = n*16 + (l&15);
        int g = (ks*4 + (l>>4)) ^ (rk&7);
        bf16x8 kf = *(const bf16x8*)(Klds[cur] + rk*64 + g*8);
        sf[n] = __builtin_amdgcn_mfma_f32_16x16x32_bf16(qf[ks], kf, sf[n], 0,0,0);
      }
    }
    __builtin_amdgcn_s_setprio(0);
    #pragma unroll
    for (int j=0;j<4;j++){
      float pm = fmaxf(fmaxf(sf[0][j], sf[1][j]), fmaxf(sf[2][j], sf[3][j]));
      pm = fmaxf(pm, __shfl_xor(pm,1)); pm = fmaxf(pm, __shfl_xor(pm,2));
      pm = fmaxf(pm, __shfl_xor(pm,4)); pm = fmaxf(pm, __shfl_xor(pm,8));
      float mn = fmaxf(mj[j], pm);
      float corr = __expf(mj[j]-mn);
      mj[j] = mn;
      float rs = 0.f;
      #pragma unroll
      for (int n=0;n<4;n++){
        float p = __expf(sf[n][j]-mn);
        sf[n][j] = p; rs += p;
      }
      rs += __shfl_xor(rs,1); rs += __shfl_xor(rs,2);
      rs += __shfl_xor(rs,4); rs += __shfl_xor(rs,8);
      lj[j] = lj[j]*corr + rs;
      #pragma unroll
      for (int n=0;n<4;n++) acc[n][j] *= corr;
    }
    #pragma unroll
    for (int j=0;j<4;j++)
      #pragma unroll
      for (int n=0;n<4;n++)
        Plds[w][((l>>4)*4+j)*72 + n*16 + (l&15)] = f2b(sf[n][j]);
    __builtin_amdgcn_s_setprio(1);
    #pragma unroll
    for (int ks=0;ks<2;ks++){
      bf16x8 pf = *(const bf16x8*)(&Plds[w][(l&15)*72 + ks*32 + (l>>4)*8]);
      #pragma unroll
      for (int n=0;n<4;n++){
        int rv = n*16 + (l&15);
        int g = (ks*4 + (l>>4)) ^ (rv&7);
        bf16x8 vf = *(const bf16x8*)(Vlds[cur] + rv*64 + g*8);
        acc[n] = __builtin_amdgcn_mfma_f32_16x16x32_bf16(pf, vf, acc[n], 0,0,0);
      }
    }
    __builtin_amdgcn_s_setprio(0);
    __syncthreads();
  }
  #pragma unroll
  for (int n=0;n<4;n++)
    #pragma unroll
    for (int j=0;j<4;j++){
      int srow = q0 + w*16 + (l>>4)*4 + j;
      int col = h*64 + n*16 + (l&15);
      float v = acc[n][j] / lj[j];
      afinal[(size_t)(b*SLEN+srow)*NFUSE + col] = f2b(v);
    }
}

// ---------------- launch ----------------
extern "C" void kernel_launch(void* const* d_in, const int* in_sizes, int n_in,
                              void* d_out, int out_size, void* d_ws, size_t ws_size,
                              hipStream_t stream) {
  const float* inputs = (const float*)d_in[0];
  const float* te     = (const float*)d_in[1];
  const float* ln_w   = (const float*)d_in[2];
  const float* ln_b   = (const float*)d_in[3];
  const float* cond_w = (const float*)d_in[4];
  const float* cond_b = (const float*)d_in[5];
  const float* w_in   = (const float*)d_in[6];
  const float* w_attn = (const float*)d_in[7];
  const float* w_ff   = (const float*)d_in[8];
  const float* b_ff   = (const float*)d_in[9];
  float* out = (float*)d_out;

  char* ws = (char*)d_ws;
  size_t off = 0;
  auto alloc = [&](size_t n)->char*{ char* p = ws + off; off += (n + 255) & ~(size_t)255; return p; };
  u16*  w_inT    = (u16*)alloc((size_t)NPROJ*DMODEL*2);
  u16*  w_fusedT = (u16*)alloc((size_t)DMODEL*NFUSE*2);
  u16*  units    = (u16*)alloc((size_t)MROWS*DMODEL*2);
  u16*  qh       = (u16*)alloc((size_t)MROWS*DMODEL*2);
  u16*  kh       = (u16*)alloc((size_t)MROWS*DMODEL*2);
  u16*  vq       = (u16*)alloc((size_t)MROWS*DMODEL*2);
  u16*  vT       = (u16*)alloc((size_t)MROWS*DMODEL*2);
  u16*  afinal   = (u16*)alloc((size_t)MROWS*NFUSE*2);
  float* pb      = (float*)alloc((size_t)4*MROWS*DMODEL*4);
  float* cond    = (float*)alloc(2*2048*4);
  float* ropetab = (float*)alloc((size_t)SLEN*32*4);
  (void)ws_size; (void)in_sizes; (void)n_in; (void)out_size;

  // weight prep
  k_transpose<1><<<dim3(NPROJ/32, DMODEL/32), 256, 0, stream>>>(w_in, NPROJ, w_inT, DMODEL, 0);
  k_transpose<0><<<dim3(DMODEL/32, DMODEL/32), 256, 0, stream>>>(w_attn, DMODEL, w_fusedT, NFUSE, 0);
  k_transpose<0><<<dim3(DMODEL/32, 4096/32), 256, 0, stream>>>(w_ff, DMODEL, w_fusedT, NFUSE, DMODEL);
  k_rope_table<<<128, 256, 0, stream>>>(ropetab);
  // conditioning + LN
  k_cond<<<dim3(8,2), 256, 0, stream>>>(te, cond_w, cond_b, cond);
  k_ln<<<MROWS, 256, 0, stream>>>(inputs, ln_w, ln_b, cond, units);
  // fused qkv/ff projection with fused rope/V/ff-gate epilogue
  k_gemm_proj<<<dim3(NPROJ/128, MROWS/128), 256, 0, stream>>>(units, w_inT, ropetab, qh, kh, vq, afinal);
  // V transpose
  k_vtrans<<<dim3(SLEN/64, 16, 2), 256, 0, stream>>>(vq, vT);
  // attention -> afinal cols 0..1023
  k_attn<<<dim3(SLEN/64, 16, 2), 256, 0, stream>>>(qh, kh, vT, afinal);
  // final fused GEMM: split-K partials, then reduce with residual + bias
  k_gemm_split<<<dim3(DMODEL/128, MROWS/128, 4), 256, 0, stream>>>(afinal, w_fusedT, pb);
  k_reduce<<<dim3(MROWS*DMODEL/1024), 256, 0, stream>>>(pb, inputs, b_ff, out);
}

// Round 3
// 370.243 us; speedup vs baseline: 1.3604x; 1.1696x over previous
//
#include <hip/hip_runtime.h>
#include <hip/hip_bf16.h>

typedef __attribute__((ext_vector_type(8))) __bf16 bf16x8;
typedef __attribute__((ext_vector_type(4))) float f32x4;
typedef unsigned short u16;
typedef unsigned int u32;

#define DMODEL 1024
#define SLEN   2048
#define NPROJ  11264
#define NFUSE  5120
#define MROWS  4096

__device__ __forceinline__ float b2f(u16 u){ u32 v=((u32)u)<<16; float f; __builtin_memcpy(&f,&v,4); return f; }
__device__ __forceinline__ u16 f2b(float f){ u32 u; __builtin_memcpy(&u,&f,4); u32 r=u+0x7fffu+((u>>16)&1u); return (u16)(r>>16); }

__device__ __forceinline__ void gload16(const void* g, void* l){
  __builtin_amdgcn_global_load_lds((__attribute__((address_space(1))) u32*)g,
                                   (__attribute__((address_space(3))) u32*)l, 16, 0, 0);
}

// ---------------- transpose+cast fp32 (K,N) -> bf16 (N, ldd) at column offset ----------------
template<int REMAP>
__global__ __launch_bounds__(256) void k_transpose(const float* __restrict__ src, int N,
                                                   u16* __restrict__ dst, int ldd, int coloff){
  __shared__ float tile[32][33];
  int n0 = blockIdx.x*32, k0 = blockIdx.y*32;
  int tx = threadIdx.x & 31, ty = threadIdx.x >> 5;
  int srccol;
  if (REMAP && (n0 + tx) >= 3072){
    int c = n0 + tx - 3072;
    int q = c >> 5, o = c & 31;
    srccol = (o < 16) ? (3072 + 16*q + o) : (7168 + 16*q + (o-16));
  } else srccol = n0 + tx;
  #pragma unroll
  for (int r=0;r<4;r++)
    tile[ty*4+r][tx] = src[(size_t)(k0+ty*4+r)*N + srccol];
  __syncthreads();
  #pragma unroll
  for (int r=0;r<4;r++){
    int n = ty*4+r;
    dst[(size_t)(n0+n)*ldd + coloff + k0 + tx] = f2b(tile[tx][n]);
  }
}

// ---------------- rope cos/sin table ----------------
__global__ __launch_bounds__(256) void k_rope_table(float* __restrict__ tab){
  int idx = blockIdx.x*256 + threadIdx.x;
  if (idx >= SLEN*16) return;
  int s = idx >> 4, i = idx & 15;
  float inv = powf(10000.f, -(float)i/16.f);
  float f = (float)s * inv;
  tab[s*32 + i]      = cosf(f);
  tab[s*32 + 16 + i] = sinf(f);
}

// ---------------- cond = silu(te) @ cond_w + cond_b ----------------
__global__ __launch_bounds__(256) void k_cond(const float* __restrict__ te, const float* __restrict__ cw,
                                              const float* __restrict__ cb, float* __restrict__ cond){
  __shared__ float sl[DMODEL];
  int b = blockIdx.y, t = threadIdx.x;
  for (int i=t;i<DMODEL;i+=256){ float x = te[b*DMODEL+i]; sl[i] = x/(1.f+expf(-x)); }
  __syncthreads();
  int n = blockIdx.x*256 + t;
  float acc = 0.f;
  for (int k=0;k<DMODEL;k++) acc += sl[k]*cw[(size_t)k*2048 + n];
  cond[b*2048+n] = acc + cb[n];
}

// ---------------- LayerNorm + modulation -> units bf16 ----------------
__global__ __launch_bounds__(256) void k_ln(const float* __restrict__ x, const float* __restrict__ lw,
                                            const float* __restrict__ lb, const float* __restrict__ cond,
                                            u16* __restrict__ units){
  int row = blockIdx.x; int b = row >> 11;
  int t = threadIdx.x;
  const float4 v = *(const float4*)(x + (size_t)row*DMODEL + t*4);
  float s = v.x+v.y+v.z+v.w;
  float q = v.x*v.x+v.y*v.y+v.z*v.z+v.w*v.w;
  #pragma unroll
  for (int off=32; off; off>>=1){ s += __shfl_xor(s,off); q += __shfl_xor(q,off); }
  __shared__ float red[8];
  int w = t>>6, l = t&63;
  if (l==0){ red[w]=s; red[4+w]=q; }
  __syncthreads();
  float S = red[0]+red[1]+red[2]+red[3];
  float Q = red[4]+red[5]+red[6]+red[7];
  float mu = S*(1.f/1024.f);
  float var = Q*(1.f/1024.f) - mu*mu;
  float rstd = rsqrtf(var + 1e-5f);
  int c0 = t*4;
  u16 o[4];
  const float* vf = (const float*)&v;
  #pragma unroll
  for (int i=0;i<4;i++){
    int c = c0+i;
    float nrm = (vf[i]-mu)*rstd*lw[c] + lb[c];
    float outv = (1.f + cond[b*2048 + c])*nrm + cond[b*2048 + 1024 + c];
    o[i] = f2b(outv);
  }
  u32 p0 = (u32)o[0] | ((u32)o[1]<<16);
  u32 p1 = (u32)o[2] | ((u32)o[3]<<16);
  uint2 pk; pk.x = p0; pk.y = p1;
  *(uint2*)(units + (size_t)row*DMODEL + c0) = pk;
}

// ================= pipelined GEMM: counted-vmcnt, raw barriers, 3 LDS buffers =================
// EPI 0: proj epilogue (rope/headsplit/v/ff-gate). EPI 1: split-K fp32 partials.
template<int BM,int BN,int WM,int WN,int NBUF,int MINW,int EPI>
__global__ __launch_bounds__(WM*WN*64, MINW) void k_gemm_pipe(
    const u16* __restrict__ A, const u16* __restrict__ Bt, int K, int lda, int ldb,
    const float* __restrict__ tab, u16* __restrict__ qh, u16* __restrict__ kh,
    u16* __restrict__ vq, u16* __restrict__ afinal, float* __restrict__ pb)
{
  constexpr int THREADS = WM*WN*64;
  constexpr int MR = BM/WM/16, NR = BN/WN/16;
  constexpr int BUFE = (BM+BN)*32;              // elems per buffer (A then B)
  __shared__ __attribute__((aligned(16))) u16 lds[NBUF*BUFE];
  int t = threadIdx.x, w = t>>6, l = t&63;
  int wr = w/WN, wc = w%WN;
  int lane16 = l&15, lg = l>>4;

  // bijective XCD swizzle (nwg % 8 == 0 for all our launches)
  int nbx = gridDim.x;
  int wg = blockIdx.y*nbx + blockIdx.x;
  int nwg = nbx*gridDim.y;
  int cpx = nwg>>3;
  int swz = (wg&7)*cpx + (wg>>3);
  int bx = swz % nbx, by = swz / nbx;

  size_t m0 = (size_t)by*BM, n0 = (size_t)bx*BN;
  int koff = (EPI==1) ? blockIdx.z*1280 : 0;
  const u16* Ag = A + m0*lda + koff;
  const u16* Bg = Bt + n0*ldb + koff;

  f32x4 zero = {0.f,0.f,0.f,0.f};
  f32x4 acc[MR][NR];
  #pragma unroll
  for (int i=0;i<MR;i++)
    #pragma unroll
    for (int j=0;j<NR;j++) acc[i][j] = zero;

  const int ntiles = K/32;

  auto STAGE = [&](int tt, int buf){
    int k0 = tt*32;
    char* Ad = (char*)lds + (size_t)buf*(BUFE*2);
    char* Bd = Ad + BM*64;
    #pragma unroll
    for (int i=0;i<2;i++){
      int s = i*THREADS + t;
      int r = s>>2, g = s&3;
      int src = (g ^ ((r>>1)&3))*8;           // inverse-swizzled global source granule
      gload16(Ag + (size_t)r*lda + k0 + src, Ad + (i*THREADS + w*64)*16);
      gload16(Bg + (size_t)r*ldb + k0 + src, Bd + (i*THREADS + w*64)*16);
    }
  };

  #pragma unroll
  for (int p=0;p<NBUF-1;p++) STAGE(p, p);

  int cur = 0;
  for (int kt=0; kt<ntiles; ++kt){
    int rem = ntiles-1-kt;
    if constexpr (NBUF==4){
      if (rem>=2)      asm volatile("s_waitcnt vmcnt(8)" ::: "memory");
      else if (rem==1) asm volatile("s_waitcnt vmcnt(4)" ::: "memory");
      else             asm volatile("s_waitcnt vmcnt(0)" ::: "memory");
    } else {
      if (rem>=1)      asm volatile("s_waitcnt vmcnt(4)" ::: "memory");
      else             asm volatile("s_waitcnt vmcnt(0)" ::: "memory");
    }
    __builtin_amdgcn_s_barrier();
    const u16* As = lds + (size_t)cur*BUFE;
    const u16* Bs = As + BM*32;
    bf16x8 af[MR], bf[NR];
    #pragma unroll
    for (int i=0;i<MR;i++){
      int r = wr*(MR*16) + i*16 + lane16;
      int g = lg ^ ((r>>1)&3);
      af[i] = *(const bf16x8*)(As + r*32 + g*8);
    }
    #pragma unroll
    for (int j=0;j<NR;j++){
      int r = wc*(NR*16) + j*16 + lane16;
      int g = lg ^ ((r>>1)&3);
      bf[j] = *(const bf16x8*)(Bs + r*32 + g*8);
    }
    int st = kt + NBUF-1;
    if (st < ntiles) STAGE(st, (cur==0)?(NBUF-1):(cur-1));
    __builtin_amdgcn_s_setprio(1);
    #pragma unroll
    for (int i=0;i<MR;i++)
      #pragma unroll
      for (int j=0;j<NR;j++)
        acc[i][j] = __builtin_amdgcn_mfma_f32_16x16x32_bf16(af[i], bf[j], acc[i][j], 0,0,0);
    __builtin_amdgcn_s_setprio(0);
    __builtin_amdgcn_sched_barrier(0);
    cur = (cur+1==NBUF)?0:(cur+1);
  }

  if constexpr (EPI==0){
    int region = (n0 < 3072) ? (int)(n0>>10) : 3;
    if (region<=1){
      u16* dst = (region==0)? qh : kh;
      float sc = (region==0)? 0.125f : 1.0f;
      int h = (int)((n0 & 1023)>>6) + wc;
      int d = lane16;
      #pragma unroll
      for (int i=0;i<MR;i++){
        #pragma unroll
        for (int r=0;r<4;r++){
          int row = (int)m0 + wr*(MR*16) + i*16 + lg*4 + r;
          int bb = row>>11, s = row&2047;
          float cs = tab[s*32+d], sn = tab[s*32+16+d];
          float x0 = acc[i][0][r], x1 = acc[i][1][r];
          size_t base = ((size_t)(bb*16+h)*SLEN + s)*64;
          dst[base+d]    = f2b((x0*cs - x1*sn)*sc);
          dst[base+16+d] = f2b((x1*cs + x0*sn)*sc);
          dst[base+32+d] = f2b(acc[i][2][r]*sc);
          dst[base+48+d] = f2b(acc[i][3][r]*sc);
        }
      }
    } else if (region==2){
      #pragma unroll
      for (int i=0;i<MR;i++)
        #pragma unroll
        for (int j=0;j<NR;j++){
          int cv = (int)(n0-2048) + wc*64 + j*16 + lane16;
          #pragma unroll
          for (int r=0;r<4;r++){
            int row = (int)m0 + wr*(MR*16) + i*16 + lg*4 + r;
            vq[(size_t)row*DMODEL + cv] = f2b(acc[i][j][r]);
          }
        }
    } else {
      int fbase = (int)((n0-3072)>>1) + wc*32 + lane16;
      #pragma unroll
      for (int i=0;i<MR;i++)
        #pragma unroll
        for (int p=0;p<2;p++){
          int col = 1024 + fbase + p*16;
          #pragma unroll
          for (int r=0;r<4;r++){
            int row = (int)m0 + wr*(MR*16) + i*16 + lg*4 + r;
            float fv = acc[i][2*p][r];
            float gv = acc[i][2*p+1][r];
            float tz = 0.7978845608f*(gv + 0.044715f*gv*gv*gv);
            float th = 1.f - 2.f/(__expf(2.f*tz)+1.f);
            afinal[(size_t)row*NFUSE + col] = f2b(fv * 0.5f*gv*(1.f+th));
          }
        }
    }
  } else {
    float* pbs = pb + (size_t)blockIdx.z*MROWS*DMODEL;
    #pragma unroll
    for (int i=0;i<MR;i++)
      #pragma unroll
      for (int j=0;j<NR;j++){
        int col = (int)n0 + wc*(NR*16) + j*16 + lane16;
        #pragma unroll
        for (int r=0;r<4;r++){
          int row = (int)m0 + wr*(MR*16) + i*16 + lg*4 + r;
          pbs[(size_t)row*DMODEL + col] = acc[i][j][r];
        }
      }
  }
}

// ---------------- reduce partials + residual + bias ----------------
__global__ __launch_bounds__(256) void k_reduce(const float* __restrict__ pb, const float* __restrict__ resid,
                                                const float* __restrict__ bias, float* __restrict__ out){
  size_t i4 = ((size_t)blockIdx.x*256 + threadIdx.x)*4;
  float4 a0 = *(const float4*)(pb + i4);
  float4 a1 = *(const float4*)(pb + (size_t)MROWS*DMODEL + i4);
  float4 a2 = *(const float4*)(pb + (size_t)2*MROWS*DMODEL + i4);
  float4 a3 = *(const float4*)(pb + (size_t)3*MROWS*DMODEL + i4);
  float4 rv = *(const float4*)(resid + i4);
  float4 bv = *(const float4*)(bias + (i4 & 1023));
  float4 o;
  o.x = a0.x+a1.x+a2.x+a3.x+rv.x+bv.x;
  o.y = a0.y+a1.y+a2.y+a3.y+rv.y+bv.y;
  o.z = a0.z+a1.z+a2.z+a3.z+rv.z+bv.z;
  o.w = a0.w+a1.w+a2.w+a3.w+rv.w+bv.w;
  *(float4*)(out + i4) = o;
}

// ---------------- V transpose: vq (B,S,1024) -> vT (B,H,64,S) ----------------
__global__ __launch_bounds__(256) void k_vtrans(const u16* __restrict__ vq, u16* __restrict__ vt){
  int b = blockIdx.z, h = blockIdx.y, s0 = blockIdx.x*64;
  int t = threadIdx.x;
  __shared__ u16 vt_lds[64][72];
  int sl = t>>2, quad = t&3;
  const u16* prow = vq + (size_t)(b*SLEN + s0 + sl)*DMODEL + h*64;
  #pragma unroll
  for (int i=0;i<16;i++){
    int d = quad*16+i;
    vt_lds[d][sl] = prow[d];
  }
  __syncthreads();
  int d = t>>2, sg = t&3;
  size_t base = ((size_t)(b*16+h)*64 + d)*SLEN + s0 + sg*16;
  #pragma unroll
  for (int i=0;i<16;i++)
    vt[base + i] = vt_lds[d][sg*16+i];
}

// ---------------- flash attention: QBLK=128, 4 waves x 32 rows, head->XCD swizzle ----------------
__global__ __launch_bounds__(256,2) void k_attn(const u16* __restrict__ qh, const u16* __restrict__ kh,
                                                const u16* __restrict__ vt, u16* __restrict__ afinal){
  __shared__ __attribute__((aligned(16))) u16 Klds[2][64*64];
  __shared__ __attribute__((aligned(16))) u16 Vlds[2][64*64];
  __shared__ __attribute__((aligned(16))) u16 Plds[4][32*72];
  // head->XCD swizzle: all 16 q-tiles of one (b,h) land on one XCD
  int p = (blockIdx.z*16 + blockIdx.y)*16 + blockIdx.x;
  int c = p&7, k = p>>3;
  int hb = c + 8*(k&3);
  int qx = k>>2;
  int b = hb>>4, h = hb&15, q0 = qx*128;
  int t = threadIdx.x, w = t>>6, l = t&63;
  int lane16 = l&15, lg = l>>4;
  size_t hoff = (size_t)(b*16+h)*SLEN*64;
  const u16* Qb = qh + hoff + (size_t)(q0 + w*32)*64;
  const u16* Kb = kh + hoff;
  const u16* Vb = vt + hoff;
  bf16x8 qf[2][2];
  #pragma unroll
  for (int mi=0;mi<2;mi++)
    #pragma unroll
    for (int ks=0;ks<2;ks++)
      qf[mi][ks] = *(const bf16x8*)(Qb + (size_t)(mi*16+lane16)*64 + ks*32 + lg*8);
  f32x4 zero = {0.f,0.f,0.f,0.f};
  f32x4 acc[2][4];
  float mj[2][4], lj[2][4];
  #pragma unroll
  for (int mi=0;mi<2;mi++)
    #pragma unroll
    for (int n=0;n<4;n++) acc[mi][n] = zero;
  #pragma unroll
  for (int mi=0;mi<2;mi++)
    #pragma unroll
    for (int jr=0;jr<4;jr++){ mj[mi][jr] = -1e30f; lj[mi][jr] = 0.f; }

  auto STAGE = [&](int buf, int kv0){
    #pragma unroll
    for (int r=0;r<2;r++){
      int cc = r*256 + t;
      int row = cc>>3;
      int g = (cc&7) ^ (row&7);
      gload16(Kb + (size_t)(kv0+row)*64 + g*8, (char*)Klds[buf] + r*4096 + w*1024);
      gload16(Vb + (size_t)row*SLEN + kv0 + g*8, (char*)Vlds[buf] + r*4096 + w*1024);
    }
  };

  STAGE(0, 0);
  __syncthreads();

  for (int tile=0; tile<SLEN/64; ++tile){
    int cur = tile & 1;
    if (tile+1 < SLEN/64) STAGE(cur^1, (tile+1)*64);
    f32x4 sf[2][4];
    #pragma unroll
    for (int mi=0;mi<2;mi++)
      #pragma unroll
      for (int n=0;n<4;n++) sf[mi][n] = zero;
    __builtin_amdgcn_s_setprio(1);
    #pragma unroll
    for (int n=0;n<4;n++){
      #pragma unroll
      for (int ks=0;ks<2;ks++){
        int rk = n*16 + lane16;
        int g = (ks*4 + lg) ^ (rk&7);
        bf16x8 kf = *(const bf16x8*)(Klds[cur] + rk*64 + g*8);
        sf[0][n] = __builtin_amdgcn_mfma_f32_16x16x32_bf16(qf[0][ks], kf, sf[0][n], 0,0,0);
        sf[1][n] = __builtin_amdgcn_mfma_f32_16x16x32_bf16(qf[1][ks], kf, sf[1][n], 0,0,0);
      }
    }
    __builtin_amdgcn_s_setprio(0);
    #pragma unroll
    for (int mi=0;mi<2;mi++)
      #pragma unroll
      for (int jr=0;jr<4;jr++){
        float pm = fmaxf(fmaxf(sf[mi][0][jr], sf[mi][1][jr]), fmaxf(sf[mi][2][jr], sf[mi][3][jr]));
        pm = fmaxf(pm, __shfl_xor(pm,1)); pm = fmaxf(pm, __shfl_xor(pm,2));
        pm = fmaxf(pm, __shfl_xor(pm,4)); pm = fmaxf(pm, __shfl_xor(pm,8));
        float mn = fmaxf(mj[mi][jr], pm);
        float corr = __expf(mj[mi][jr]-mn);
        mj[mi][jr] = mn;
        float rs = 0.f;
        #pragma unroll
        for (int n=0;n<4;n++){
          float pv = __expf(sf[mi][n][jr]-mn);
          sf[mi][n][jr] = pv; rs += pv;
        }
        rs += __shfl_xor(rs,1); rs += __shfl_xor(rs,2);
        rs += __shfl_xor(rs,4); rs += __shfl_xor(rs,8);
        lj[mi][jr] = lj[mi][jr]*corr + rs;
        #pragma unroll
        for (int n=0;n<4;n++) acc[mi][n][jr] *= corr;
      }
    #pragma unroll
    for (int mi=0;mi<2;mi++)
      #pragma unroll
      for (int jr=0;jr<4;jr++)
        #pragma unroll
        for (int n=0;n<4;n++)
          Plds[w][(mi*16 + lg*4 + jr)*72 + n*16 + lane16] = f2b(sf[mi][n][jr]);
    __builtin_amdgcn_s_setprio(1);
    #pragma unroll
    for (int ks=0;ks<2;ks++){
      bf16x8 vf[4];
      #pragma unroll
      for (int n=0;n<4;n++){
        int rv = n*16 + lane16;
        int g = (ks*4 + lg) ^ (rv&7);
        vf[n] = *(const bf16x8*)(Vlds[cur] + rv*64 + g*8);
      }
      #pragma unroll
      for (int mi=0;mi<2;mi++){
        bf16x8 pa = *(const bf16x8*)(&Plds[w][(mi*16 + lane16)*72 + ks*32 + lg*8]);
        #pragma unroll
        for (int n=0;n<4;n++)
          acc[mi][n] = __builtin_amdgcn_mfma_f32_16x16x32_bf16(pa, vf[n], acc[mi][n], 0,0,0);
      }
    }
    __builtin_amdgcn_s_setprio(0);
    __syncthreads();
  }
  #pragma unroll
  for (int mi=0;mi<2;mi++)
    #pragma unroll
    for (int n=0;n<4;n++)
      #pragma unroll
      for (int jr=0;jr<4;jr++){
        int srow = q0 + w*32 + mi*16 + lg*4 + jr;
        int col = h*64 + n*16 + lane16;
        float v = acc[mi][n][jr] / lj[mi][jr];
        afinal[(size_t)(b*SLEN+srow)*NFUSE + col] = f2b(v);
      }
}

// ---------------- launch ----------------
extern "C" void kernel_launch(void* const* d_in, const int* in_sizes, int n_in,
                              void* d_out, int out_size, void* d_ws, size_t ws_size,
                              hipStream_t stream) {
  const float* inputs = (const float*)d_in[0];
  const float* te     = (const float*)d_in[1];
  const float* ln_w   = (const float*)d_in[2];
  const float* ln_b   = (const float*)d_in[3];
  const float* cond_w = (const float*)d_in[4];
  const float* cond_b = (const float*)d_in[5];
  const float* w_in   = (const float*)d_in[6];
  const float* w_attn = (const float*)d_in[7];
  const float* w_ff   = (const float*)d_in[8];
  const float* b_ff   = (const float*)d_in[9];
  float* out = (float*)d_out;

  char* ws = (char*)d_ws;
  size_t off = 0;
  auto alloc = [&](size_t n)->char*{ char* p = ws + off; off += (n + 255) & ~(size_t)255; return p; };
  u16*  w_inT    = (u16*)alloc((size_t)NPROJ*DMODEL*2);
  u16*  w_fusedT = (u16*)alloc((size_t)DMODEL*NFUSE*2);
  u16*  units    = (u16*)alloc((size_t)MROWS*DMODEL*2);
  u16*  qh       = (u16*)alloc((size_t)MROWS*DMODEL*2);
  u16*  kh       = (u16*)alloc((size_t)MROWS*DMODEL*2);
  u16*  vq       = (u16*)alloc((size_t)MROWS*DMODEL*2);
  u16*  vT       = (u16*)alloc((size_t)MROWS*DMODEL*2);
  u16*  afinal   = (u16*)alloc((size_t)MROWS*NFUSE*2);
  float* pb      = (float*)alloc((size_t)4*MROWS*DMODEL*4);
  float* cond    = (float*)alloc(2*2048*4);
  float* ropetab = (float*)alloc((size_t)SLEN*32*4);
  (void)ws_size; (void)in_sizes; (void)n_in; (void)out_size;

  // weight prep
  k_transpose<1><<<dim3(NPROJ/32, DMODEL/32), 256, 0, stream>>>(w_in, NPROJ, w_inT, DMODEL, 0);
  k_transpose<0><<<dim3(DMODEL/32, DMODEL/32), 256, 0, stream>>>(w_attn, DMODEL, w_fusedT, NFUSE, 0);
  k_transpose<0><<<dim3(DMODEL/32, 4096/32), 256, 0, stream>>>(w_ff, DMODEL, w_fusedT, NFUSE, DMODEL);
  k_rope_table<<<128, 256, 0, stream>>>(ropetab);
  // conditioning + LN
  k_cond<<<dim3(8,2), 256, 0, stream>>>(te, cond_w, cond_b, cond);
  k_ln<<<MROWS, 256, 0, stream>>>(inputs, ln_w, ln_b, cond, units);
  // fused qkv/ff projection (pipelined 256x256) with fused rope/V/ff-gate epilogue
  k_gemm_pipe<256,256,2,4,3,2,0><<<dim3(NPROJ/256, MROWS/256), 512, 0, stream>>>(
      units, w_inT, DMODEL, DMODEL, DMODEL, ropetab, qh, kh, vq, afinal, nullptr);
  // V transpose
  k_vtrans<<<dim3(SLEN/64, 16, 2), 256, 0, stream>>>(vq, vT);
  // attention -> afinal cols 0..1023
  k_attn<<<dim3(SLEN/128, 16, 2), 256, 0, stream>>>(qh, kh, vT, afinal);
  // final fused GEMM: split-K partials (pipelined 128x128), then reduce
  k_gemm_pipe<128,128,2,2,3,3,1><<<dim3(DMODEL/128, MROWS/128, 4), 256, 0, stream>>>(
      afinal, w_fusedT, 1280, NFUSE, NFUSE, nullptr, nullptr, nullptr, nullptr, nullptr, pb);
  k_reduce<<<dim3(MROWS*DMODEL/1024), 256, 0, stream>>>(pb, inputs, b_ff, out);
}